// Round 1
// baseline (3434.254 us; speedup 1.0000x reference)
//
#include <hip/hip_runtime.h>

#define N_NODES 10000
#define N_EDGES 160000
#define DIN     256
#define DEIN    128
#define DD      256   // hidden dim

// ---------------------------------------------------------------------------
// Kernel 1/2: pretrans GEMM + bias + ReLU.  out[M,256] = relu(A[M,K] @ W[K,256] + b)
// Block: 256 threads, tile = 32 rows x 256 cols. A-tile staged in LDS.
// ---------------------------------------------------------------------------
template <int K>
__global__ __launch_bounds__(256) void pretrans_kernel(
    const float* __restrict__ A, const float* __restrict__ W,
    const float* __restrict__ b, float* __restrict__ out, int M) {
  __shared__ float sA[32 * K];
  const int row0 = blockIdx.x * 32;
  const int tid  = threadIdx.x;

  for (int i = tid; i < 32 * K; i += 256) {
    const int r = i / K, k = i % K;
    const int row = row0 + r;
    sA[i] = (row < M) ? A[(size_t)row * K + k] : 0.f;
  }
  __syncthreads();

  const int d = tid;
  float acc[32];
#pragma unroll
  for (int r = 0; r < 32; ++r) acc[r] = 0.f;

  for (int k = 0; k < K; ++k) {
    const float w = W[k * 256 + d];
#pragma unroll
    for (int r = 0; r < 32; ++r) acc[r] += sA[r * K + k] * w;
  }

  const float bias = b[d];
#pragma unroll
  for (int r = 0; r < 32; ++r) {
    const int row = row0 + r;
    if (row < M) {
      float v = acc[r] + bias;
      out[(size_t)row * 256 + d] = v > 0.f ? v : 0.f;
    }
  }
}

// ---------------------------------------------------------------------------
// Kernel 3: degree histogram
// ---------------------------------------------------------------------------
__global__ void degree_kernel(const int* __restrict__ src, const int* __restrict__ dst,
                              float* __restrict__ deg_in, float* __restrict__ deg_out) {
  const int e = blockIdx.x * 256 + threadIdx.x;
  if (e < N_EDGES) {
    atomicAdd(&deg_out[src[e]], 1.f);
    atomicAdd(&deg_in[dst[e]], 1.f);
  }
}

// ---------------------------------------------------------------------------
// Kernel 4: fused per-edge compute.
// For a tile of TE=16 edges: gather h = [pre_n[src] | pre_e | pre_n[dst]] (768)
// into LDS, then each thread (= one output column d) sweeps K once computing
//   msg_p = relu(h[0:512]   @ Wpa + bpa)  -> atomicAdd agg_p[dst]
//   msg_s = relu(h[512:768],h[256:512] @ Wsa + bsa) -> atomicAdd agg_s[src]
//   eout  =      h[0:768]   @ Wet + bet   -> edge_out
// Wsa row mapping: rows 0:256 <- pre_n[dst] (h[512:768]); rows 256:512 <- pre_e (h[256:512]).
// ---------------------------------------------------------------------------
__global__ __launch_bounds__(256) void edge_fused_kernel(
    const float* __restrict__ pre_n, const float* __restrict__ pre_e,
    const int* __restrict__ src, const int* __restrict__ dst,
    const float* __restrict__ Wpa, const float* __restrict__ bpa,
    const float* __restrict__ Wsa, const float* __restrict__ bsa,
    const float* __restrict__ Wet, const float* __restrict__ bet,
    float* __restrict__ agg_p, float* __restrict__ agg_s,
    float* __restrict__ edge_out) {
  constexpr int TE = 16;
  __shared__ float sH[TE * 768];
  __shared__ int sSrc[TE], sDst[TE];

  const int e0  = blockIdx.x * TE;   // E % TE == 0, no tail
  const int tid = threadIdx.x;

  if (tid < TE) {
    sSrc[tid] = src[e0 + tid];
    sDst[tid] = dst[e0 + tid];
  }
  __syncthreads();

  // gather: 3 coalesced 256-wide loads per edge row
  for (int r = (tid >> 8); r < TE; ++r) {  // tid>>8 == 0; loop over rows
    const int c = tid;  // 0..255
    sH[r * 768 + c]       = pre_n[(size_t)sSrc[r] * 256 + c];
    sH[r * 768 + 256 + c] = pre_e[(size_t)(e0 + r) * 256 + c];
    sH[r * 768 + 512 + c] = pre_n[(size_t)sDst[r] * 256 + c];
  }
  __syncthreads();

  const int d = tid;
  float accP[TE], accS[TE], accE[TE];
#pragma unroll
  for (int r = 0; r < TE; ++r) { accP[r] = 0.f; accS[r] = 0.f; accE[r] = 0.f; }

  // Phase A: k in [0,256)  -> h_src : feeds Wpa, Wet
  for (int k = 0; k < 256; ++k) {
    const float wpa = Wpa[k * 256 + d];
    const float wet = Wet[k * 256 + d];
#pragma unroll
    for (int r = 0; r < TE; ++r) {
      const float a = sH[r * 768 + k];
      accP[r] += a * wpa;
      accE[r] += a * wet;
    }
  }
  // Phase B: k in [256,512) -> h_e : feeds Wpa, Wsa (rows 256:512), Wet
  for (int k = 256; k < 512; ++k) {
    const float wpa = Wpa[k * 256 + d];
    const float wsa = Wsa[k * 256 + d];
    const float wet = Wet[k * 256 + d];
#pragma unroll
    for (int r = 0; r < TE; ++r) {
      const float a = sH[r * 768 + k];
      accP[r] += a * wpa;
      accS[r] += a * wsa;
      accE[r] += a * wet;
    }
  }
  // Phase C: k in [512,768) -> h_dst : feeds Wsa (rows 0:256), Wet
  for (int k = 512; k < 768; ++k) {
    const float wsa = Wsa[(k - 512) * 256 + d];
    const float wet = Wet[k * 256 + d];
#pragma unroll
    for (int r = 0; r < TE; ++r) {
      const float a = sH[r * 768 + k];
      accS[r] += a * wsa;
      accE[r] += a * wet;
    }
  }

  const float vbpa = bpa[d], vbsa = bsa[d], vbet = bet[d];
#pragma unroll
  for (int r = 0; r < TE; ++r) {
    float p = accP[r] + vbpa; p = p > 0.f ? p : 0.f;
    atomicAdd(&agg_p[(size_t)sDst[r] * 256 + d], p);
    float s = accS[r] + vbsa; s = s > 0.f ? s : 0.f;
    atomicAdd(&agg_s[(size_t)sSrc[r] * 256 + d], s);
    edge_out[(size_t)(e0 + r) * 256 + d] = accE[r] + vbet;
  }
}

// ---------------------------------------------------------------------------
// Kernel 5: node transformer.  node_out = [agg_p/deg_in | pre_n | agg_s/deg_out] @ Wnt + bnt
// Tile 32 rows; 3 phases of K=256 each, LDS re-staged per phase.
// ---------------------------------------------------------------------------
__global__ __launch_bounds__(256) void node_final_kernel(
    const float* __restrict__ pre_n, const float* __restrict__ agg_p,
    const float* __restrict__ agg_s, const float* __restrict__ deg_in,
    const float* __restrict__ deg_out, const float* __restrict__ Wnt,
    const float* __restrict__ bnt, float* __restrict__ node_out) {
  __shared__ float sA[32 * 256];
  const int row0 = blockIdx.x * 32;
  const int tid  = threadIdx.x;
  const int d    = tid;

  float acc[32];
#pragma unroll
  for (int r = 0; r < 32; ++r) acc[r] = 0.f;

  for (int phase = 0; phase < 3; ++phase) {
    // stage tile
    for (int i = tid; i < 32 * 256; i += 256) {
      const int r = i >> 8, k = i & 255;
      const int row = row0 + r;
      float v = 0.f;
      if (row < N_NODES) {
        if (phase == 0)      v = agg_p[(size_t)row * 256 + k] / fmaxf(deg_in[row], 1.f);
        else if (phase == 1) v = pre_n[(size_t)row * 256 + k];
        else                 v = agg_s[(size_t)row * 256 + k] / fmaxf(deg_out[row], 1.f);
      }
      sA[i] = v;
    }
    __syncthreads();

    const float* Wp = Wnt + (size_t)phase * 256 * 256;
    for (int k = 0; k < 256; ++k) {
      const float w = Wp[k * 256 + d];
#pragma unroll
      for (int r = 0; r < 32; ++r) acc[r] += sA[r * 256 + k] * w;
    }
    __syncthreads();
  }

  const float bias = bnt[d];
#pragma unroll
  for (int r = 0; r < 32; ++r) {
    const int row = row0 + r;
    if (row < N_NODES) node_out[(size_t)row * 256 + d] = acc[r] + bias;
  }
}

// ---------------------------------------------------------------------------
extern "C" void kernel_launch(void* const* d_in, const int* in_sizes, int n_in,
                              void* d_out, int out_size, void* d_ws, size_t ws_size,
                              hipStream_t stream) {
  const float* x         = (const float*)d_in[0];
  const float* edge_feat = (const float*)d_in[1];
  const int*   edge_idx  = (const int*)d_in[2];
  const float* Wn  = (const float*)d_in[3];
  const float* bn  = (const float*)d_in[4];
  const float* We  = (const float*)d_in[5];
  const float* be  = (const float*)d_in[6];
  const float* Wpa = (const float*)d_in[7];
  const float* bpa = (const float*)d_in[8];
  const float* Wsa = (const float*)d_in[9];
  const float* bsa = (const float*)d_in[10];
  const float* Wnt = (const float*)d_in[11];
  const float* bnt = (const float*)d_in[12];
  const float* Wet = (const float*)d_in[13];
  const float* bet = (const float*)d_in[14];

  const int* src = edge_idx;            // row 0
  const int* dst = edge_idx + N_EDGES;  // row 1

  float* node_out = (float*)d_out;                       // [N,256]
  float* edge_out = (float*)d_out + (size_t)N_NODES * DD; // [E,256]

  char* ws = (char*)d_ws;
  float* pre_n   = (float*)ws; ws += (size_t)N_NODES * DD * 4;
  float* agg_p   = (float*)ws; ws += (size_t)N_NODES * DD * 4;
  float* agg_s   = (float*)ws; ws += (size_t)N_NODES * DD * 4;
  float* deg_in  = (float*)ws; ws += (size_t)N_NODES * 4;
  float* deg_out = (float*)ws; ws += (size_t)N_NODES * 4;
  float* pre_e   = (float*)ws; ws += (size_t)N_EDGES * DD * 4;

  // zero the accumulators (agg_p, agg_s, deg_in, deg_out are contiguous)
  hipMemsetAsync(agg_p, 0, ((size_t)N_NODES * DD * 2 + (size_t)N_NODES * 2) * 4, stream);

  pretrans_kernel<DIN><<<(N_NODES + 31) / 32, 256, 0, stream>>>(x, Wn, bn, pre_n, N_NODES);
  pretrans_kernel<DEIN><<<(N_EDGES + 31) / 32, 256, 0, stream>>>(edge_feat, We, be, pre_e, N_EDGES);
  degree_kernel<<<(N_EDGES + 255) / 256, 256, 0, stream>>>(src, dst, deg_in, deg_out);
  edge_fused_kernel<<<N_EDGES / 16, 256, 0, stream>>>(
      pre_n, pre_e, src, dst, Wpa, bpa, Wsa, bsa, Wet, bet, agg_p, agg_s, edge_out);
  node_final_kernel<<<(N_NODES + 31) / 32, 256, 0, stream>>>(
      pre_n, agg_p, agg_s, deg_in, deg_out, Wnt, bnt, node_out);
}

// Round 2
// 1207.909 us; speedup vs baseline: 2.8431x; 2.8431x over previous
//
#include <hip/hip_runtime.h>
#include <hip/hip_bf16.h>

#define N_NODES 10000
#define N_EDGES 160000
#define DIN     256
#define DEIN    128
#define DD      256   // hidden dim

typedef __bf16 bf16x8 __attribute__((ext_vector_type(8)));
typedef float  f32x4  __attribute__((ext_vector_type(4)));

// ---------------------------------------------------------------------------
// Kernel 1/2: pretrans GEMM + bias + ReLU.  out = relu(A[M,K] @ W[K,256] + b)
// Writes f32 (optional) and bf16 outputs.
// ---------------------------------------------------------------------------
template <int K>
__global__ __launch_bounds__(256) void pretrans_kernel(
    const float* __restrict__ A, const float* __restrict__ W,
    const float* __restrict__ b, float* __restrict__ outf,
    __hip_bfloat16* __restrict__ outb, int M) {
  __shared__ float sA[32 * K];
  const int row0 = blockIdx.x * 32;
  const int tid  = threadIdx.x;

  for (int i = tid; i < 32 * K; i += 256) {
    const int r = i / K, k = i % K;
    const int row = row0 + r;
    sA[i] = (row < M) ? A[(size_t)row * K + k] : 0.f;
  }
  __syncthreads();

  const int d = tid;
  float acc[32];
#pragma unroll
  for (int r = 0; r < 32; ++r) acc[r] = 0.f;

  for (int k = 0; k < K; ++k) {
    const float w = W[k * 256 + d];
#pragma unroll
    for (int r = 0; r < 32; ++r) acc[r] += sA[r * K + k] * w;
  }

  const float bias = b[d];
#pragma unroll
  for (int r = 0; r < 32; ++r) {
    const int row = row0 + r;
    if (row < M) {
      float v = acc[r] + bias;
      v = v > 0.f ? v : 0.f;
      if (outf) outf[(size_t)row * 256 + d] = v;
      outb[(size_t)row * 256 + d] = __float2bfloat16(v);
    }
  }
}

// ---------------------------------------------------------------------------
// Kernel 3: degree histogram
// ---------------------------------------------------------------------------
__global__ void degree_kernel(const int* __restrict__ src, const int* __restrict__ dst,
                              float* __restrict__ deg_in, float* __restrict__ deg_out) {
  const int e = blockIdx.x * 256 + threadIdx.x;
  if (e < N_EDGES) {
    atomicAdd(&deg_out[src[e]], 1.f);
    atomicAdd(&deg_in[dst[e]], 1.f);
  }
}

// ---------------------------------------------------------------------------
// Kernel 3b: build fused transposed weight Wt[768 n][768 k] (bf16).
// h-k axis: [0,256)=pre_n[src], [256,512)=pre_e, [512,768)=pre_n[dst].
// n: [0,256)=Wpa cols, [256,512)=Wsa cols, [512,768)=Wet cols.
// Wpa rows: 0:256 <- h_src, 256:512 <- h_e.
// Wsa rows: 0:256 <- h_dst (k 512:768), 256:512 <- h_e (k 256:512).
// ---------------------------------------------------------------------------
__global__ void build_wt_kernel(const float* __restrict__ Wpa,
                                const float* __restrict__ Wsa,
                                const float* __restrict__ Wet,
                                __hip_bfloat16* __restrict__ Wt) {
  const int idx = blockIdx.x * 256 + threadIdx.x;  // n*768 + k
  if (idx >= 768 * 768) return;
  const int n = idx / 768, k = idx % 768;
  float v = 0.f;
  if (n < 256) {
    if (k < 512) v = Wpa[k * 256 + n];
  } else if (n < 512) {
    const int nn = n - 256;
    if (k >= 512) v = Wsa[(k - 512) * 256 + nn];
    else if (k >= 256) v = Wsa[k * 256 + nn];
  } else {
    v = Wet[k * 256 + (n - 512)];
  }
  Wt[idx] = __float2bfloat16(v);
}

// ---------------------------------------------------------------------------
// Kernel 4: MFMA edge GEMM (m97 structure).
// Grid: (E/128) edge-tiles x 6 n-tiles. n-tile 0,1 -> P; 2,3 -> S; 4,5 -> E.
// A[128 edges][768 k] gathered on the fly, B = Wt (n-major, k-contiguous).
// 4 waves, wave tile 64x64, BK=64, double-buffered LDS, XOR swizzle (row&7)<<4.
// ---------------------------------------------------------------------------
__global__ __launch_bounds__(256, 2) void edge_mfma_kernel(
    const __hip_bfloat16* __restrict__ pre_n,
    const __hip_bfloat16* __restrict__ pre_e,
    const __hip_bfloat16* __restrict__ Wt,
    const int* __restrict__ src, const int* __restrict__ dst,
    const float* __restrict__ bpa, const float* __restrict__ bsa,
    const float* __restrict__ bet,
    float* __restrict__ agg_p, float* __restrict__ agg_s,
    float* __restrict__ edge_out) {
  __shared__ char sA[2][16384];
  __shared__ char sW[2][16384];
  __shared__ int sSrc[128], sDst[128];

  const int bid = blockIdx.x;
  const int et  = bid / 6;
  const int nt  = bid % 6;
  const int mat = nt >> 1;           // 0=P, 1=S, 2=E
  const int e0  = et * 128;

  const int tid  = threadIdx.x;
  const int lane = tid & 63;
  const int w    = tid >> 6;

  if (tid < 128) sSrc[tid] = src[e0 + tid];
  else           sDst[tid - 128] = dst[e0 + tid - 128];
  __syncthreads();

  const int c_lo = (mat == 1) ? 4 : 0;
  const int c_hi = (mat == 0) ? 8 : 12;

  const int rsub  = lane >> 3;           // row within 8-row group
  const int pslot = lane & 7;            // physical 16B slot
  const int sslot = pslot ^ rsub;        // swizzled source slot

  auto stage = [&](int b, int c) {
#pragma unroll
    for (int j = 0; j < 4; ++j) {
      const int r = w * 32 + j * 8 + rsub;   // 0..127
      const __hip_bfloat16* gp;
      if (c < 4)      gp = pre_n + (size_t)sSrc[r] * 256 + c * 64 + sslot * 8;
      else if (c < 8) gp = pre_e + (size_t)(e0 + r) * 256 + (c - 4) * 64 + sslot * 8;
      else            gp = pre_n + (size_t)sDst[r] * 256 + (c - 8) * 64 + sslot * 8;
      __builtin_amdgcn_global_load_lds(
          (const __attribute__((address_space(1))) void*)gp,
          (__attribute__((address_space(3))) void*)&sA[b][(w * 32 + j * 8) * 128],
          16, 0, 0);
      const __hip_bfloat16* wp =
          Wt + (size_t)(nt * 128 + r) * 768 + c * 64 + sslot * 8;
      __builtin_amdgcn_global_load_lds(
          (const __attribute__((address_space(1))) void*)wp,
          (__attribute__((address_space(3))) void*)&sW[b][(w * 32 + j * 8) * 128],
          16, 0, 0);
    }
  };

  const int wm = (w >> 1) * 64;   // wave m offset (edges)
  const int wn = (w & 1) * 64;    // wave n offset (cols)

  f32x4 acc[4][4];
#pragma unroll
  for (int i = 0; i < 4; ++i)
#pragma unroll
    for (int j = 0; j < 4; ++j) acc[i][j] = (f32x4)0.f;

  stage(0, c_lo);
  asm volatile("s_waitcnt vmcnt(0)");
  __syncthreads();

  int buf = 0;
  for (int c = c_lo; c < c_hi; ++c) {
    if (c + 1 < c_hi) stage(buf ^ 1, c + 1);
#pragma unroll
    for (int kk = 0; kk < 2; ++kk) {
      bf16x8 av[4], bv[4];
#pragma unroll
      for (int i = 0; i < 4; ++i) {
        const int row  = wm + i * 16 + (lane & 15);
        const int boff = row * 128 + ((kk * 64 + (lane >> 4) * 16) ^ ((row & 7) << 4));
        av[i] = *(const bf16x8*)&sA[buf][boff];
      }
#pragma unroll
      for (int j = 0; j < 4; ++j) {
        const int nrow = wn + j * 16 + (lane & 15);
        const int boff = nrow * 128 + ((kk * 64 + (lane >> 4) * 16) ^ ((nrow & 7) << 4));
        bv[j] = *(const bf16x8*)&sW[buf][boff];
      }
#pragma unroll
      for (int i = 0; i < 4; ++i)
#pragma unroll
        for (int j = 0; j < 4; ++j)
          acc[i][j] = __builtin_amdgcn_mfma_f32_16x16x32_bf16(av[i], bv[j], acc[i][j], 0, 0, 0);
    }
    __syncthreads();
    buf ^= 1;
  }

  // epilogue: C/D layout col = lane&15, row = (lane>>4)*4 + r
  const int colbase = (nt & 1) * 128 + wn;   // col within this matrix's 256
#pragma unroll
  for (int i = 0; i < 4; ++i) {
    const int row = wm + i * 16 + ((lane >> 4) << 2);
#pragma unroll
    for (int j = 0; j < 4; ++j) {
      const int col = colbase + j * 16 + (lane & 15);
      if (mat == 0) {
        const float bb = bpa[col];
#pragma unroll
        for (int r = 0; r < 4; ++r) {
          float v = acc[i][j][r] + bb;
          v = v > 0.f ? v : 0.f;
          atomicAdd(&agg_p[(size_t)sDst[row + r] * 256 + col], v);
        }
      } else if (mat == 1) {
        const float bb = bsa[col];
#pragma unroll
        for (int r = 0; r < 4; ++r) {
          float v = acc[i][j][r] + bb;
          v = v > 0.f ? v : 0.f;
          atomicAdd(&agg_s[(size_t)sSrc[row + r] * 256 + col], v);
        }
      } else {
        const float bb = bet[col];
#pragma unroll
        for (int r = 0; r < 4; ++r)
          edge_out[(size_t)(e0 + row + r) * 256 + col] = acc[i][j][r] + bb;
      }
    }
  }
}

// ---------------------------------------------------------------------------
// Kernel 5: node transformer (unchanged, f32)
// ---------------------------------------------------------------------------
__global__ __launch_bounds__(256) void node_final_kernel(
    const float* __restrict__ pre_n, const float* __restrict__ agg_p,
    const float* __restrict__ agg_s, const float* __restrict__ deg_in,
    const float* __restrict__ deg_out, const float* __restrict__ Wnt,
    const float* __restrict__ bnt, float* __restrict__ node_out) {
  __shared__ float sA[32 * 256];
  const int row0 = blockIdx.x * 32;
  const int tid  = threadIdx.x;
  const int d    = tid;

  float acc[32];
#pragma unroll
  for (int r = 0; r < 32; ++r) acc[r] = 0.f;

  for (int phase = 0; phase < 3; ++phase) {
    for (int i = tid; i < 32 * 256; i += 256) {
      const int r = i >> 8, k = i & 255;
      const int row = row0 + r;
      float v = 0.f;
      if (row < N_NODES) {
        if (phase == 0)      v = agg_p[(size_t)row * 256 + k] / fmaxf(deg_in[row], 1.f);
        else if (phase == 1) v = pre_n[(size_t)row * 256 + k];
        else                 v = agg_s[(size_t)row * 256 + k] / fmaxf(deg_out[row], 1.f);
      }
      sA[i] = v;
    }
    __syncthreads();

    const float* Wp = Wnt + (size_t)phase * 256 * 256;
    for (int k = 0; k < 256; ++k) {
      const float w = Wp[k * 256 + d];
#pragma unroll
      for (int r = 0; r < 32; ++r) acc[r] += sA[r * 256 + k] * w;
    }
    __syncthreads();
  }

  const float bias = bnt[d];
#pragma unroll
  for (int r = 0; r < 32; ++r) {
    const int row = row0 + r;
    if (row < N_NODES) node_out[(size_t)row * 256 + d] = acc[r] + bias;
  }
}

// ---------------------------------------------------------------------------
extern "C" void kernel_launch(void* const* d_in, const int* in_sizes, int n_in,
                              void* d_out, int out_size, void* d_ws, size_t ws_size,
                              hipStream_t stream) {
  const float* x         = (const float*)d_in[0];
  const float* edge_feat = (const float*)d_in[1];
  const int*   edge_idx  = (const int*)d_in[2];
  const float* Wn  = (const float*)d_in[3];
  const float* bn  = (const float*)d_in[4];
  const float* We  = (const float*)d_in[5];
  const float* be  = (const float*)d_in[6];
  const float* Wpa = (const float*)d_in[7];
  const float* bpa = (const float*)d_in[8];
  const float* Wsa = (const float*)d_in[9];
  const float* bsa = (const float*)d_in[10];
  const float* Wnt = (const float*)d_in[11];
  const float* bnt = (const float*)d_in[12];
  const float* Wet = (const float*)d_in[13];
  const float* bet = (const float*)d_in[14];

  const int* src = edge_idx;
  const int* dst = edge_idx + N_EDGES;

  float* node_out = (float*)d_out;                        // [N,256]
  float* edge_out = (float*)d_out + (size_t)N_NODES * DD; // [E,256]

  char* ws = (char*)d_ws;
  float* pre_n   = (float*)ws; ws += (size_t)N_NODES * DD * 4;   // 10.24 MB
  float* agg_p   = (float*)ws; ws += (size_t)N_NODES * DD * 4;
  float* agg_s   = (float*)ws; ws += (size_t)N_NODES * DD * 4;
  float* deg_in  = (float*)ws; ws += (size_t)N_NODES * 4;
  float* deg_out = (float*)ws; ws += (size_t)N_NODES * 4;
  __hip_bfloat16* pre_n_bf = (__hip_bfloat16*)ws; ws += (size_t)N_NODES * DD * 2;
  __hip_bfloat16* pre_e_bf = (__hip_bfloat16*)ws; ws += (size_t)N_EDGES * DD * 2;
  __hip_bfloat16* Wt       = (__hip_bfloat16*)ws; ws += (size_t)768 * 768 * 2;

  // zero agg_p, agg_s, deg_in, deg_out (contiguous)
  hipMemsetAsync(agg_p, 0, ((size_t)N_NODES * DD * 2 + (size_t)N_NODES * 2) * 4, stream);

  build_wt_kernel<<<(768 * 768 + 255) / 256, 256, 0, stream>>>(Wpa, Wsa, Wet, Wt);
  pretrans_kernel<DIN><<<(N_NODES + 31) / 32, 256, 0, stream>>>(x, Wn, bn, pre_n, pre_n_bf, N_NODES);
  pretrans_kernel<DEIN><<<(N_EDGES + 31) / 32, 256, 0, stream>>>(edge_feat, We, be, nullptr, pre_e_bf, N_EDGES);
  degree_kernel<<<(N_EDGES + 255) / 256, 256, 0, stream>>>(src, dst, deg_in, deg_out);
  edge_mfma_kernel<<<(N_EDGES / 128) * 6, 256, 0, stream>>>(
      pre_n_bf, pre_e_bf, Wt, src, dst, bpa, bsa, bet, agg_p, agg_s, edge_out);
  node_final_kernel<<<(N_NODES + 31) / 32, 256, 0, stream>>>(
      pre_n, agg_p, agg_s, deg_in, deg_out, Wnt, bnt, node_out);
}

// Round 3
// 508.982 us; speedup vs baseline: 6.7473x; 2.3732x over previous
//
#include <hip/hip_runtime.h>
#include <hip/hip_bf16.h>

#define N_NODES 10000
#define N_EDGES 160000
#define DD      256   // hidden dim

typedef __bf16 bf16x8 __attribute__((ext_vector_type(8)));
typedef float  f32x4  __attribute__((ext_vector_type(4)));

// ---------------------------------------------------------------------------
// f32 -> bf16 convert, 8 elems/thread (n multiple of 8)
// ---------------------------------------------------------------------------
__global__ void f2b_kernel(const float* __restrict__ in,
                           __hip_bfloat16* __restrict__ out, int n) {
  const int i = (blockIdx.x * 256 + threadIdx.x) * 8;
  if (i >= n) return;
  const f32x4 a = *(const f32x4*)(in + i);
  const f32x4 b = *(const f32x4*)(in + i + 4);
  union { __hip_bfloat16 h[8]; uint4 u; } o;
#pragma unroll
  for (int j = 0; j < 4; ++j) o.h[j] = __float2bfloat16(a[j]);
#pragma unroll
  for (int j = 0; j < 4; ++j) o.h[4 + j] = __float2bfloat16(b[j]);
  *(uint4*)(out + i) = o.u;
}

// ---------------------------------------------------------------------------
// W[K,256] f32 -> Wt[256,K] bf16 (transpose + convert)
// ---------------------------------------------------------------------------
__global__ void wtrans_kernel(const float* __restrict__ W,
                              __hip_bfloat16* __restrict__ Wt, int K) {
  const int idx = blockIdx.x * 256 + threadIdx.x;  // n*K + k
  if (idx >= 256 * K) return;
  const int n = idx / K, k = idx % K;
  Wt[idx] = __float2bfloat16(W[k * 256 + n]);
}

// ---------------------------------------------------------------------------
// build fused edge weight Wt[768 n][768 k] bf16 (same mapping as before)
// ---------------------------------------------------------------------------
__global__ void build_wt_kernel(const float* __restrict__ Wpa,
                                const float* __restrict__ Wsa,
                                const float* __restrict__ Wet,
                                __hip_bfloat16* __restrict__ Wt) {
  const int idx = blockIdx.x * 256 + threadIdx.x;  // n*768 + k
  if (idx >= 768 * 768) return;
  const int n = idx / 768, k = idx % 768;
  float v = 0.f;
  if (n < 256) {
    if (k < 512) v = Wpa[k * 256 + n];
  } else if (n < 512) {
    const int nn = n - 256;
    if (k >= 512) v = Wsa[(k - 512) * 256 + nn];
    else if (k >= 256) v = Wsa[k * 256 + nn];
  } else {
    v = Wet[k * 256 + (n - 512)];
  }
  Wt[idx] = __float2bfloat16(v);
}

// ---------------------------------------------------------------------------
// degree histogram
// ---------------------------------------------------------------------------
__global__ void degree_kernel(const int* __restrict__ src, const int* __restrict__ dst,
                              float* __restrict__ deg_in, float* __restrict__ deg_out) {
  const int e = blockIdx.x * 256 + threadIdx.x;
  if (e < N_EDGES) {
    atomicAdd(&deg_out[src[e]], 1.f);
    atomicAdd(&deg_in[dst[e]], 1.f);
  }
}

// ---------------------------------------------------------------------------
// Generic MFMA GEMM (m97 structure): out[M,256] = act(A[M,K] @ Wt^T + bias)
// A bf16 row-major [M,K]; Wt bf16 [256,K] (n-major, k-contig). K = Ksteps*64.
// Grid: (ceil(M/128), 2). 4 waves, 64x64 wave tile, double-buffered swizzled LDS.
// ---------------------------------------------------------------------------
template <bool RELU, bool F32OUT>
__global__ __launch_bounds__(256, 2) void gemm_mfma_kernel(
    const __hip_bfloat16* __restrict__ A, const __hip_bfloat16* __restrict__ Wt,
    const float* __restrict__ bias, float* __restrict__ outf,
    __hip_bfloat16* __restrict__ outb, int M, int Ksteps) {
  __shared__ char sA[2][16384];
  __shared__ char sW[2][16384];

  const int K    = Ksteps * 64;
  const int row0 = blockIdx.x * 128;
  const int nt   = blockIdx.y;  // 0/1 -> output cols [nt*128, nt*128+128)

  const int tid  = threadIdx.x;
  const int lane = tid & 63;
  const int w    = tid >> 6;

  const int rsub  = lane >> 3;
  const int pslot = lane & 7;
  const int sslot = pslot ^ rsub;

  auto stage = [&](int b, int c) {
#pragma unroll
    for (int j = 0; j < 4; ++j) {
      const int r = w * 32 + j * 8 + rsub;
      int ar = row0 + r;
      if (ar >= M) ar = M - 1;
      const __hip_bfloat16* gp = A + (size_t)ar * K + c * 64 + sslot * 8;
      __builtin_amdgcn_global_load_lds(
          (const __attribute__((address_space(1))) void*)gp,
          (__attribute__((address_space(3))) void*)&sA[b][(w * 32 + j * 8) * 128],
          16, 0, 0);
      const __hip_bfloat16* wp = Wt + (size_t)(nt * 128 + r) * K + c * 64 + sslot * 8;
      __builtin_amdgcn_global_load_lds(
          (const __attribute__((address_space(1))) void*)wp,
          (__attribute__((address_space(3))) void*)&sW[b][(w * 32 + j * 8) * 128],
          16, 0, 0);
    }
  };

  const int wm = (w >> 1) * 64;
  const int wn = (w & 1) * 64;

  f32x4 acc[4][4];
#pragma unroll
  for (int i = 0; i < 4; ++i)
#pragma unroll
    for (int j = 0; j < 4; ++j) acc[i][j] = (f32x4)0.f;

  stage(0, 0);
  asm volatile("s_waitcnt vmcnt(0)");
  __syncthreads();

  int buf = 0;
  for (int c = 0; c < Ksteps; ++c) {
    if (c + 1 < Ksteps) stage(buf ^ 1, c + 1);
#pragma unroll
    for (int kk = 0; kk < 2; ++kk) {
      bf16x8 av[4], bv[4];
#pragma unroll
      for (int i = 0; i < 4; ++i) {
        const int row  = wm + i * 16 + (lane & 15);
        const int boff = row * 128 + ((kk * 64 + (lane >> 4) * 16) ^ ((row & 7) << 4));
        av[i] = *(const bf16x8*)&sA[buf][boff];
      }
#pragma unroll
      for (int j = 0; j < 4; ++j) {
        const int nrow = wn + j * 16 + (lane & 15);
        const int boff = nrow * 128 + ((kk * 64 + (lane >> 4) * 16) ^ ((nrow & 7) << 4));
        bv[j] = *(const bf16x8*)&sW[buf][boff];
      }
#pragma unroll
      for (int i = 0; i < 4; ++i)
#pragma unroll
        for (int j = 0; j < 4; ++j)
          acc[i][j] = __builtin_amdgcn_mfma_f32_16x16x32_bf16(av[i], bv[j], acc[i][j], 0, 0, 0);
    }
    __syncthreads();
    buf ^= 1;
  }

  // epilogue: C/D layout col = lane&15, row = (lane>>4)*4 + r
#pragma unroll
  for (int i = 0; i < 4; ++i) {
    const int row = row0 + wm + i * 16 + ((lane >> 4) << 2);
#pragma unroll
    for (int j = 0; j < 4; ++j) {
      const int col = nt * 128 + wn + j * 16 + (lane & 15);
      const float bb = bias[col];
#pragma unroll
      for (int r = 0; r < 4; ++r) {
        if (row + r < M) {
          float v = acc[i][j][r] + bb;
          if (RELU) v = v > 0.f ? v : 0.f;
          if (F32OUT) outf[(size_t)(row + r) * 256 + col] = v;
          else        outb[(size_t)(row + r) * 256 + col] = __float2bfloat16(v);
        }
      }
    }
  }
}

// ---------------------------------------------------------------------------
// MFMA edge GEMM (unchanged from round 2 — verified).
// ---------------------------------------------------------------------------
__global__ __launch_bounds__(256, 2) void edge_mfma_kernel(
    const __hip_bfloat16* __restrict__ pre_n,
    const __hip_bfloat16* __restrict__ pre_e,
    const __hip_bfloat16* __restrict__ Wt,
    const int* __restrict__ src, const int* __restrict__ dst,
    const float* __restrict__ bpa, const float* __restrict__ bsa,
    const float* __restrict__ bet,
    float* __restrict__ agg_p, float* __restrict__ agg_s,
    float* __restrict__ edge_out) {
  __shared__ char sA[2][16384];
  __shared__ char sW[2][16384];
  __shared__ int sSrc[128], sDst[128];

  const int bid = blockIdx.x;
  const int et  = bid / 6;
  const int nt  = bid % 6;
  const int mat = nt >> 1;  // 0=P, 1=S, 2=E
  const int e0  = et * 128;

  const int tid  = threadIdx.x;
  const int lane = tid & 63;
  const int w    = tid >> 6;

  if (tid < 128) sSrc[tid] = src[e0 + tid];
  else           sDst[tid - 128] = dst[e0 + tid - 128];
  __syncthreads();

  const int c_lo = (mat == 1) ? 4 : 0;
  const int c_hi = (mat == 0) ? 8 : 12;

  const int rsub  = lane >> 3;
  const int pslot = lane & 7;
  const int sslot = pslot ^ rsub;

  auto stage = [&](int b, int c) {
#pragma unroll
    for (int j = 0; j < 4; ++j) {
      const int r = w * 32 + j * 8 + rsub;
      const __hip_bfloat16* gp;
      if (c < 4)      gp = pre_n + (size_t)sSrc[r] * 256 + c * 64 + sslot * 8;
      else if (c < 8) gp = pre_e + (size_t)(e0 + r) * 256 + (c - 4) * 64 + sslot * 8;
      else            gp = pre_n + (size_t)sDst[r] * 256 + (c - 8) * 64 + sslot * 8;
      __builtin_amdgcn_global_load_lds(
          (const __attribute__((address_space(1))) void*)gp,
          (__attribute__((address_space(3))) void*)&sA[b][(w * 32 + j * 8) * 128],
          16, 0, 0);
      const __hip_bfloat16* wp =
          Wt + (size_t)(nt * 128 + r) * 768 + c * 64 + sslot * 8;
      __builtin_amdgcn_global_load_lds(
          (const __attribute__((address_space(1))) void*)wp,
          (__attribute__((address_space(3))) void*)&sW[b][(w * 32 + j * 8) * 128],
          16, 0, 0);
    }
  };

  const int wm = (w >> 1) * 64;
  const int wn = (w & 1) * 64;

  f32x4 acc[4][4];
#pragma unroll
  for (int i = 0; i < 4; ++i)
#pragma unroll
    for (int j = 0; j < 4; ++j) acc[i][j] = (f32x4)0.f;

  stage(0, c_lo);
  asm volatile("s_waitcnt vmcnt(0)");
  __syncthreads();

  int buf = 0;
  for (int c = c_lo; c < c_hi; ++c) {
    if (c + 1 < c_hi) stage(buf ^ 1, c + 1);
#pragma unroll
    for (int kk = 0; kk < 2; ++kk) {
      bf16x8 av[4], bv[4];
#pragma unroll
      for (int i = 0; i < 4; ++i) {
        const int row  = wm + i * 16 + (lane & 15);
        const int boff = row * 128 + ((kk * 64 + (lane >> 4) * 16) ^ ((row & 7) << 4));
        av[i] = *(const bf16x8*)&sA[buf][boff];
      }
#pragma unroll
      for (int j = 0; j < 4; ++j) {
        const int nrow = wn + j * 16 + (lane & 15);
        const int boff = nrow * 128 + ((kk * 64 + (lane >> 4) * 16) ^ ((nrow & 7) << 4));
        bv[j] = *(const bf16x8*)&sW[buf][boff];
      }
#pragma unroll
      for (int i = 0; i < 4; ++i)
#pragma unroll
        for (int j = 0; j < 4; ++j)
          acc[i][j] = __builtin_amdgcn_mfma_f32_16x16x32_bf16(av[i], bv[j], acc[i][j], 0, 0, 0);
    }
    __syncthreads();
    buf ^= 1;
  }

  const int colbase = (nt & 1) * 128 + wn;
#pragma unroll
  for (int i = 0; i < 4; ++i) {
    const int row = wm + i * 16 + ((lane >> 4) << 2);
#pragma unroll
    for (int j = 0; j < 4; ++j) {
      const int col = colbase + j * 16 + (lane & 15);
      if (mat == 0) {
        const float bb = bpa[col];
#pragma unroll
        for (int r = 0; r < 4; ++r) {
          float v = acc[i][j][r] + bb;
          v = v > 0.f ? v : 0.f;
          atomicAdd(&agg_p[(size_t)sDst[row + r] * 256 + col], v);
        }
      } else if (mat == 1) {
        const float bb = bsa[col];
#pragma unroll
        for (int r = 0; r < 4; ++r) {
          float v = acc[i][j][r] + bb;
          v = v > 0.f ? v : 0.f;
          atomicAdd(&agg_s[(size_t)sSrc[row + r] * 256 + col], v);
        }
      } else {
        const float bb = bet[col];
#pragma unroll
        for (int r = 0; r < 4; ++r)
          edge_out[(size_t)(e0 + row + r) * 256 + col] = acc[i][j][r] + bb;
      }
    }
  }
}

// ---------------------------------------------------------------------------
// node input assembly: nodeH[N,768] = bf16([agg_p/deg_in | pre_n | agg_s/deg_out])
// ---------------------------------------------------------------------------
__global__ void node_prep_kernel(const float* __restrict__ agg_p,
                                 const float* __restrict__ agg_s,
                                 const __hip_bfloat16* __restrict__ pre_n,
                                 const float* __restrict__ deg_in,
                                 const float* __restrict__ deg_out,
                                 __hip_bfloat16* __restrict__ nodeH) {
  const int row = blockIdx.x;
  const int c   = threadIdx.x;
  const float di = fmaxf(deg_in[row], 1.f);
  const float dо = fmaxf(deg_out[row], 1.f);
  nodeH[(size_t)row * 768 + c]       = __float2bfloat16(agg_p[(size_t)row * 256 + c] / di);
  nodeH[(size_t)row * 768 + 256 + c] = pre_n[(size_t)row * 256 + c];
  nodeH[(size_t)row * 768 + 512 + c] = __float2bfloat16(agg_s[(size_t)row * 256 + c] / dо);
}

// ---------------------------------------------------------------------------
extern "C" void kernel_launch(void* const* d_in, const int* in_sizes, int n_in,
                              void* d_out, int out_size, void* d_ws, size_t ws_size,
                              hipStream_t stream) {
  const float* x         = (const float*)d_in[0];
  const float* edge_feat = (const float*)d_in[1];
  const int*   edge_idx  = (const int*)d_in[2];
  const float* Wn  = (const float*)d_in[3];
  const float* bn  = (const float*)d_in[4];
  const float* We  = (const float*)d_in[5];
  const float* be  = (const float*)d_in[6];
  const float* Wpa = (const float*)d_in[7];
  const float* bpa = (const float*)d_in[8];
  const float* Wsa = (const float*)d_in[9];
  const float* bsa = (const float*)d_in[10];
  const float* Wnt = (const float*)d_in[11];
  const float* bnt = (const float*)d_in[12];
  const float* Wet = (const float*)d_in[13];
  const float* bet = (const float*)d_in[14];

  const int* src = edge_idx;
  const int* dst = edge_idx + N_EDGES;

  float* node_out = (float*)d_out;
  float* edge_out = (float*)d_out + (size_t)N_NODES * DD;

  char* ws = (char*)d_ws;
  float* agg_p   = (float*)ws; ws += (size_t)N_NODES * DD * 4;
  float* agg_s   = (float*)ws; ws += (size_t)N_NODES * DD * 4;
  float* deg_in  = (float*)ws; ws += (size_t)N_NODES * 4;
  float* deg_out = (float*)ws; ws += (size_t)N_NODES * 4;
  __hip_bfloat16* x_bf     = (__hip_bfloat16*)ws; ws += (size_t)N_NODES * DD * 2;
  __hip_bfloat16* ef_bf    = (__hip_bfloat16*)ws; ws += (size_t)N_EDGES * 128 * 2;
  __hip_bfloat16* pre_n_bf = (__hip_bfloat16*)ws; ws += (size_t)N_NODES * DD * 2;
  __hip_bfloat16* pre_e_bf = (__hip_bfloat16*)ws; ws += (size_t)N_EDGES * DD * 2;
  __hip_bfloat16* nodeH    = (__hip_bfloat16*)ws; ws += (size_t)N_NODES * 768 * 2;
  __hip_bfloat16* Wt_edge  = (__hip_bfloat16*)ws; ws += (size_t)768 * 768 * 2;
  __hip_bfloat16* Wn_t     = (__hip_bfloat16*)ws; ws += (size_t)256 * 256 * 2;
  __hip_bfloat16* We_t     = (__hip_bfloat16*)ws; ws += (size_t)256 * 128 * 2;
  __hip_bfloat16* Wnt_t    = (__hip_bfloat16*)ws; ws += (size_t)256 * 768 * 2;

  // zero agg_p, agg_s, deg_in, deg_out (contiguous)
  hipMemsetAsync(agg_p, 0, ((size_t)N_NODES * DD * 2 + (size_t)N_NODES * 2) * 4, stream);

  f2b_kernel<<<N_NODES * DD / 8 / 256, 256, 0, stream>>>(x, x_bf, N_NODES * DD);
  f2b_kernel<<<N_EDGES * 128 / 8 / 256, 256, 0, stream>>>(edge_feat, ef_bf, N_EDGES * 128);
  wtrans_kernel<<<(256 * 256 + 255) / 256, 256, 0, stream>>>(Wn, Wn_t, 256);
  wtrans_kernel<<<(256 * 128 + 255) / 256, 256, 0, stream>>>(We, We_t, 128);
  wtrans_kernel<<<(256 * 768 + 255) / 256, 256, 0, stream>>>(Wnt, Wnt_t, 768);
  build_wt_kernel<<<(768 * 768 + 255) / 256, 256, 0, stream>>>(Wpa, Wsa, Wet, Wt_edge);
  degree_kernel<<<(N_EDGES + 255) / 256, 256, 0, stream>>>(src, dst, deg_in, deg_out);

  // pretrans GEMMs (relu, bf16 out)
  {
    dim3 g((N_NODES + 127) / 128, 2);
    gemm_mfma_kernel<true, false><<<g, 256, 0, stream>>>(
        x_bf, Wn_t, bn, nullptr, pre_n_bf, N_NODES, 4);
  }
  {
    dim3 g(N_EDGES / 128, 2);
    gemm_mfma_kernel<true, false><<<g, 256, 0, stream>>>(
        ef_bf, We_t, be, nullptr, pre_e_bf, N_EDGES, 2);
  }

  edge_mfma_kernel<<<(N_EDGES / 128) * 6, 256, 0, stream>>>(
      pre_n_bf, pre_e_bf, Wt_edge, src, dst, bpa, bsa, bet, agg_p, agg_s, edge_out);

  node_prep_kernel<<<N_NODES, 256, 0, stream>>>(agg_p, agg_s, pre_n_bf, deg_in, deg_out, nodeH);

  {
    dim3 g((N_NODES + 127) / 128, 2);
    gemm_mfma_kernel<false, true><<<g, 256, 0, stream>>>(
        nodeH, Wnt_t, bnt, node_out, nullptr, N_NODES, 12);
  }
}

// Round 4
// 505.874 us; speedup vs baseline: 6.7888x; 1.0061x over previous
//
#include <hip/hip_runtime.h>
#include <hip/hip_bf16.h>

#define N_NODES 10000
#define N_EDGES 160000
#define DD      256   // hidden dim

typedef __bf16 bf16x8 __attribute__((ext_vector_type(8)));
typedef float  f32x4  __attribute__((ext_vector_type(4)));

// ---------------------------------------------------------------------------
// f32 -> bf16 convert, 8 elems/thread (n multiple of 8)
// ---------------------------------------------------------------------------
__global__ void f2b_kernel(const float* __restrict__ in,
                           __hip_bfloat16* __restrict__ out, int n) {
  const int i = (blockIdx.x * 256 + threadIdx.x) * 8;
  if (i >= n) return;
  const f32x4 a = *(const f32x4*)(in + i);
  const f32x4 b = *(const f32x4*)(in + i + 4);
  union { __hip_bfloat16 h[8]; uint4 u; } o;
#pragma unroll
  for (int j = 0; j < 4; ++j) o.h[j] = __float2bfloat16(a[j]);
#pragma unroll
  for (int j = 0; j < 4; ++j) o.h[4 + j] = __float2bfloat16(b[j]);
  *(uint4*)(out + i) = o.u;
}

// ---------------------------------------------------------------------------
// W[K,256] f32 -> Wt[256,K] bf16 (transpose + convert)
// ---------------------------------------------------------------------------
__global__ void wtrans_kernel(const float* __restrict__ W,
                              __hip_bfloat16* __restrict__ Wt, int K) {
  const int idx = blockIdx.x * 256 + threadIdx.x;  // n*K + k
  if (idx >= 256 * K) return;
  const int n = idx / K, k = idx % K;
  Wt[idx] = __float2bfloat16(W[k * 256 + n]);
}

// ---------------------------------------------------------------------------
// build fused edge weight Wt[768 n][768 k] bf16
// h-k axis: [0,256)=pre_n[src], [256,512)=pre_e, [512,768)=pre_n[dst].
// ---------------------------------------------------------------------------
__global__ void build_wt_kernel(const float* __restrict__ Wpa,
                                const float* __restrict__ Wsa,
                                const float* __restrict__ Wet,
                                __hip_bfloat16* __restrict__ Wt) {
  const int idx = blockIdx.x * 256 + threadIdx.x;  // n*768 + k
  if (idx >= 768 * 768) return;
  const int n = idx / 768, k = idx % 768;
  float v = 0.f;
  if (n < 256) {
    if (k < 512) v = Wpa[k * 256 + n];
  } else if (n < 512) {
    const int nn = n - 256;
    if (k >= 512) v = Wsa[(k - 512) * 256 + nn];
    else if (k >= 256) v = Wsa[k * 256 + nn];
  } else {
    v = Wet[k * 256 + (n - 512)];
  }
  Wt[idx] = __float2bfloat16(v);
}

// ---------------------------------------------------------------------------
// degree histogram
// ---------------------------------------------------------------------------
__global__ void degree_kernel(const int* __restrict__ src, const int* __restrict__ dst,
                              float* __restrict__ deg_in, float* __restrict__ deg_out) {
  const int e = blockIdx.x * 256 + threadIdx.x;
  if (e < N_EDGES) {
    atomicAdd(&deg_out[src[e]], 1.f);
    atomicAdd(&deg_in[dst[e]], 1.f);
  }
}

// ---------------------------------------------------------------------------
// Generic MFMA GEMM (m97 structure): out[M,256] = act(A[M,K] @ Wt^T + bias)
// ---------------------------------------------------------------------------
template <bool RELU, bool F32OUT>
__global__ __launch_bounds__(256, 2) void gemm_mfma_kernel(
    const __hip_bfloat16* __restrict__ A, const __hip_bfloat16* __restrict__ Wt,
    const float* __restrict__ bias, float* __restrict__ outf,
    __hip_bfloat16* __restrict__ outb, int M, int Ksteps) {
  __shared__ char sA[2][16384];
  __shared__ char sW[2][16384];

  const int K    = Ksteps * 64;
  const int row0 = blockIdx.x * 128;
  const int nt   = blockIdx.y;

  const int tid  = threadIdx.x;
  const int lane = tid & 63;
  const int w    = tid >> 6;

  const int rsub  = lane >> 3;
  const int pslot = lane & 7;
  const int sslot = pslot ^ rsub;

  auto stage = [&](int b, int c) {
#pragma unroll
    for (int j = 0; j < 4; ++j) {
      const int r = w * 32 + j * 8 + rsub;
      int ar = row0 + r;
      if (ar >= M) ar = M - 1;
      const __hip_bfloat16* gp = A + (size_t)ar * K + c * 64 + sslot * 8;
      __builtin_amdgcn_global_load_lds(
          (const __attribute__((address_space(1))) void*)gp,
          (__attribute__((address_space(3))) void*)&sA[b][(w * 32 + j * 8) * 128],
          16, 0, 0);
      const __hip_bfloat16* wp = Wt + (size_t)(nt * 128 + r) * K + c * 64 + sslot * 8;
      __builtin_amdgcn_global_load_lds(
          (const __attribute__((address_space(1))) void*)wp,
          (__attribute__((address_space(3))) void*)&sW[b][(w * 32 + j * 8) * 128],
          16, 0, 0);
    }
  };

  const int wm = (w >> 1) * 64;
  const int wn = (w & 1) * 64;

  f32x4 acc[4][4];
#pragma unroll
  for (int i = 0; i < 4; ++i)
#pragma unroll
    for (int j = 0; j < 4; ++j) acc[i][j] = (f32x4)0.f;

  stage(0, 0);
  asm volatile("s_waitcnt vmcnt(0)");
  __syncthreads();

  int buf = 0;
  for (int c = 0; c < Ksteps; ++c) {
    if (c + 1 < Ksteps) stage(buf ^ 1, c + 1);
#pragma unroll
    for (int kk = 0; kk < 2; ++kk) {
      bf16x8 av[4], bv[4];
#pragma unroll
      for (int i = 0; i < 4; ++i) {
        const int row  = wm + i * 16 + (lane & 15);
        const int boff = row * 128 + ((kk * 64 + (lane >> 4) * 16) ^ ((row & 7) << 4));
        av[i] = *(const bf16x8*)&sA[buf][boff];
      }
#pragma unroll
      for (int j = 0; j < 4; ++j) {
        const int nrow = wn + j * 16 + (lane & 15);
        const int boff = nrow * 128 + ((kk * 64 + (lane >> 4) * 16) ^ ((nrow & 7) << 4));
        bv[j] = *(const bf16x8*)&sW[buf][boff];
      }
#pragma unroll
      for (int i = 0; i < 4; ++i)
#pragma unroll
        for (int j = 0; j < 4; ++j)
          acc[i][j] = __builtin_amdgcn_mfma_f32_16x16x32_bf16(av[i], bv[j], acc[i][j], 0, 0, 0);
    }
    __syncthreads();
    buf ^= 1;
  }

#pragma unroll
  for (int i = 0; i < 4; ++i) {
    const int row = row0 + wm + i * 16 + ((lane >> 4) << 2);
#pragma unroll
    for (int j = 0; j < 4; ++j) {
      const int col = nt * 128 + wn + j * 16 + (lane & 15);
      const float bb = bias[col];
#pragma unroll
      for (int r = 0; r < 4; ++r) {
        if (row + r < M) {
          float v = acc[i][j][r] + bb;
          if (RELU) v = v > 0.f ? v : 0.f;
          if (F32OUT) outf[(size_t)(row + r) * 256 + col] = v;
          else        outb[(size_t)(row + r) * 256 + col] = __float2bfloat16(v);
        }
      }
    }
  }
}

// ---------------------------------------------------------------------------
// MFMA edge GEMM with XCD-grouped block remap:
// all 6 nt-blocks of an edge-tile land on one XCD so the pre_e tile and
// gathered pre_n rows are HBM-fetched once and L2-shared.
// Grid = 7504 (938 slots x 8 XCDs); slots s -> (et = s/6, nt = s%6).
// ---------------------------------------------------------------------------
__global__ __launch_bounds__(256, 2) void edge_mfma_kernel(
    const __hip_bfloat16* __restrict__ pre_n,
    const __hip_bfloat16* __restrict__ pre_e,
    const __hip_bfloat16* __restrict__ Wt,
    const int* __restrict__ src, const int* __restrict__ dst,
    const float* __restrict__ bpa, const float* __restrict__ bsa,
    const float* __restrict__ bet,
    float* __restrict__ agg_p, float* __restrict__ agg_s,
    float* __restrict__ edge_out) {
  __shared__ char sA[2][16384];
  __shared__ char sW[2][16384];
  __shared__ int sSrc[128], sDst[128];

  // XCD-grouped remap (bid -> XCD is bid % 8 on MI355X)
  const int bid  = blockIdx.x;
  const int xcd  = bid & 7;
  const int s    = xcd * 938 + (bid >> 3);
  const int et   = s / 6;
  const int nt   = s % 6;
  if (et >= N_EDGES / 128) return;
  const int mat = nt >> 1;  // 0=P, 1=S, 2=E
  const int e0  = et * 128;

  const int tid  = threadIdx.x;
  const int lane = tid & 63;
  const int w    = tid >> 6;

  if (tid < 128) sSrc[tid] = src[e0 + tid];
  else           sDst[tid - 128] = dst[e0 + tid - 128];
  __syncthreads();

  const int c_lo = (mat == 1) ? 4 : 0;
  const int c_hi = (mat == 0) ? 8 : 12;

  const int rsub  = lane >> 3;
  const int pslot = lane & 7;
  const int sslot = pslot ^ rsub;

  auto stage = [&](int b, int c) {
#pragma unroll
    for (int j = 0; j < 4; ++j) {
      const int r = w * 32 + j * 8 + rsub;
      const __hip_bfloat16* gp;
      if (c < 4)      gp = pre_n + (size_t)sSrc[r] * 256 + c * 64 + sslot * 8;
      else if (c < 8) gp = pre_e + (size_t)(e0 + r) * 256 + (c - 4) * 64 + sslot * 8;
      else            gp = pre_n + (size_t)sDst[r] * 256 + (c - 8) * 64 + sslot * 8;
      __builtin_amdgcn_global_load_lds(
          (const __attribute__((address_space(1))) void*)gp,
          (__attribute__((address_space(3))) void*)&sA[b][(w * 32 + j * 8) * 128],
          16, 0, 0);
      const __hip_bfloat16* wp =
          Wt + (size_t)(nt * 128 + r) * 768 + c * 64 + sslot * 8;
      __builtin_amdgcn_global_load_lds(
          (const __attribute__((address_space(1))) void*)wp,
          (__attribute__((address_space(3))) void*)&sW[b][(w * 32 + j * 8) * 128],
          16, 0, 0);
    }
  };

  const int wm = (w >> 1) * 64;
  const int wn = (w & 1) * 64;

  f32x4 acc[4][4];
#pragma unroll
  for (int i = 0; i < 4; ++i)
#pragma unroll
    for (int j = 0; j < 4; ++j) acc[i][j] = (f32x4)0.f;

  stage(0, c_lo);
  asm volatile("s_waitcnt vmcnt(0)");
  __syncthreads();

  int buf = 0;
  for (int c = c_lo; c < c_hi; ++c) {
    if (c + 1 < c_hi) stage(buf ^ 1, c + 1);
#pragma unroll
    for (int kk = 0; kk < 2; ++kk) {
      bf16x8 av[4], bv[4];
#pragma unroll
      for (int i = 0; i < 4; ++i) {
        const int row  = wm + i * 16 + (lane & 15);
        const int boff = row * 128 + ((kk * 64 + (lane >> 4) * 16) ^ ((row & 7) << 4));
        av[i] = *(const bf16x8*)&sA[buf][boff];
      }
#pragma unroll
      for (int j = 0; j < 4; ++j) {
        const int nrow = wn + j * 16 + (lane & 15);
        const int boff = nrow * 128 + ((kk * 64 + (lane >> 4) * 16) ^ ((nrow & 7) << 4));
        bv[j] = *(const bf16x8*)&sW[buf][boff];
      }
#pragma unroll
      for (int i = 0; i < 4; ++i)
#pragma unroll
        for (int j = 0; j < 4; ++j)
          acc[i][j] = __builtin_amdgcn_mfma_f32_16x16x32_bf16(av[i], bv[j], acc[i][j], 0, 0, 0);
    }
    __syncthreads();
    buf ^= 1;
  }

  const int colbase = (nt & 1) * 128 + wn;
#pragma unroll
  for (int i = 0; i < 4; ++i) {
    const int row = wm + i * 16 + ((lane >> 4) << 2);
#pragma unroll
    for (int j = 0; j < 4; ++j) {
      const int col = colbase + j * 16 + (lane & 15);
      if (mat == 0) {
        const float bb = bpa[col];
#pragma unroll
        for (int r = 0; r < 4; ++r) {
          float v = acc[i][j][r] + bb;
          v = v > 0.f ? v : 0.f;
          atomicAdd(&agg_p[(size_t)sDst[row + r] * 256 + col], v);
        }
      } else if (mat == 1) {
        const float bb = bsa[col];
#pragma unroll
        for (int r = 0; r < 4; ++r) {
          float v = acc[i][j][r] + bb;
          v = v > 0.f ? v : 0.f;
          atomicAdd(&agg_s[(size_t)sSrc[row + r] * 256 + col], v);
        }
      } else {
        const float bb = bet[col];
#pragma unroll
        for (int r = 0; r < 4; ++r)
          edge_out[(size_t)(e0 + row + r) * 256 + col] = acc[i][j][r] + bb;
      }
    }
  }
}

// ---------------------------------------------------------------------------
// node input assembly: nodeH[N,768] = bf16([agg_p/deg_in | pre_n | agg_s/deg_out])
// ---------------------------------------------------------------------------
__global__ void node_prep_kernel(const float* __restrict__ agg_p,
                                 const float* __restrict__ agg_s,
                                 const __hip_bfloat16* __restrict__ pre_n,
                                 const float* __restrict__ deg_in,
                                 const float* __restrict__ deg_out,
                                 __hip_bfloat16* __restrict__ nodeH) {
  const int row = blockIdx.x;
  const int c   = threadIdx.x;
  const float di = fmaxf(deg_in[row], 1.f);
  const float dd = fmaxf(deg_out[row], 1.f);
  nodeH[(size_t)row * 768 + c]       = __float2bfloat16(agg_p[(size_t)row * 256 + c] / di);
  nodeH[(size_t)row * 768 + 256 + c] = pre_n[(size_t)row * 256 + c];
  nodeH[(size_t)row * 768 + 512 + c] = __float2bfloat16(agg_s[(size_t)row * 256 + c] / dd);
}

// ---------------------------------------------------------------------------
extern "C" void kernel_launch(void* const* d_in, const int* in_sizes, int n_in,
                              void* d_out, int out_size, void* d_ws, size_t ws_size,
                              hipStream_t stream) {
  const float* x         = (const float*)d_in[0];
  const float* edge_feat = (const float*)d_in[1];
  const int*   edge_idx  = (const int*)d_in[2];
  const float* Wn  = (const float*)d_in[3];
  const float* bn  = (const float*)d_in[4];
  const float* We  = (const float*)d_in[5];
  const float* be  = (const float*)d_in[6];
  const float* Wpa = (const float*)d_in[7];
  const float* bpa = (const float*)d_in[8];
  const float* Wsa = (const float*)d_in[9];
  const float* bsa = (const float*)d_in[10];
  const float* Wnt = (const float*)d_in[11];
  const float* bnt = (const float*)d_in[12];
  const float* Wet = (const float*)d_in[13];
  const float* bet = (const float*)d_in[14];

  const int* src = edge_idx;
  const int* dst = edge_idx + N_EDGES;

  float* node_out = (float*)d_out;
  float* edge_out = (float*)d_out + (size_t)N_NODES * DD;

  char* ws = (char*)d_ws;
  float* agg_p   = (float*)ws; ws += (size_t)N_NODES * DD * 4;
  float* agg_s   = (float*)ws; ws += (size_t)N_NODES * DD * 4;
  float* deg_in  = (float*)ws; ws += (size_t)N_NODES * 4;
  float* deg_out = (float*)ws; ws += (size_t)N_NODES * 4;
  __hip_bfloat16* x_bf     = (__hip_bfloat16*)ws; ws += (size_t)N_NODES * DD * 2;
  __hip_bfloat16* ef_bf    = (__hip_bfloat16*)ws; ws += (size_t)N_EDGES * 128 * 2;
  __hip_bfloat16* pre_n_bf = (__hip_bfloat16*)ws; ws += (size_t)N_NODES * DD * 2;
  __hip_bfloat16* pre_e_bf = (__hip_bfloat16*)ws; ws += (size_t)N_EDGES * DD * 2;
  __hip_bfloat16* nodeH    = (__hip_bfloat16*)ws; ws += (size_t)N_NODES * 768 * 2;
  __hip_bfloat16* Wt_edge  = (__hip_bfloat16*)ws; ws += (size_t)768 * 768 * 2;
  __hip_bfloat16* Wn_t     = (__hip_bfloat16*)ws; ws += (size_t)256 * 256 * 2;
  __hip_bfloat16* We_t     = (__hip_bfloat16*)ws; ws += (size_t)256 * 128 * 2;
  __hip_bfloat16* Wnt_t    = (__hip_bfloat16*)ws; ws += (size_t)256 * 768 * 2;

  hipMemsetAsync(agg_p, 0, ((size_t)N_NODES * DD * 2 + (size_t)N_NODES * 2) * 4, stream);

  f2b_kernel<<<N_NODES * DD / 8 / 256, 256, 0, stream>>>(x, x_bf, N_NODES * DD);
  f2b_kernel<<<N_EDGES * 128 / 8 / 256, 256, 0, stream>>>(edge_feat, ef_bf, N_EDGES * 128);
  wtrans_kernel<<<(256 * 256 + 255) / 256, 256, 0, stream>>>(Wn, Wn_t, 256);
  wtrans_kernel<<<(256 * 128 + 255) / 256, 256, 0, stream>>>(We, We_t, 128);
  wtrans_kernel<<<(256 * 768 + 255) / 256, 256, 0, stream>>>(Wnt, Wnt_t, 768);
  build_wt_kernel<<<(768 * 768 + 255) / 256, 256, 0, stream>>>(Wpa, Wsa, Wet, Wt_edge);
  degree_kernel<<<(N_EDGES + 255) / 256, 256, 0, stream>>>(src, dst, deg_in, deg_out);

  {
    dim3 g((N_NODES + 127) / 128, 2);
    gemm_mfma_kernel<true, false><<<g, 256, 0, stream>>>(
        x_bf, Wn_t, bn, nullptr, pre_n_bf, N_NODES, 4);
  }
  {
    dim3 g(N_EDGES / 128, 2);
    gemm_mfma_kernel<true, false><<<g, 256, 0, stream>>>(
        ef_bf, We_t, be, nullptr, pre_e_bf, N_EDGES, 2);
  }

  edge_mfma_kernel<<<7504, 256, 0, stream>>>(
      pre_n_bf, pre_e_bf, Wt_edge, src, dst, bpa, bsa, bet, agg_p, agg_s, edge_out);

  node_prep_kernel<<<N_NODES, 256, 0, stream>>>(agg_p, agg_s, pre_n_bf, deg_in, deg_out, nodeH);

  {
    dim3 g((N_NODES + 127) / 128, 2);
    gemm_mfma_kernel<false, true><<<g, 256, 0, stream>>>(
        nodeH, Wnt_t, bnt, node_out, nullptr, N_NODES, 12);
  }
}

// Round 5
// 501.858 us; speedup vs baseline: 6.8431x; 1.0080x over previous
//
#include <hip/hip_runtime.h>
#include <hip/hip_bf16.h>

#define N_NODES 10000
#define N_EDGES 160000
#define DD      256   // hidden dim

typedef __bf16 bf16x8 __attribute__((ext_vector_type(8)));
typedef float  f32x4  __attribute__((ext_vector_type(4)));

// ---------------------------------------------------------------------------
// W[K,256] f32 -> Wt[256,K] bf16 (transpose + convert)
// ---------------------------------------------------------------------------
__global__ void wtrans_kernel(const float* __restrict__ W,
                              __hip_bfloat16* __restrict__ Wt, int K) {
  const int idx = blockIdx.x * 256 + threadIdx.x;  // n*K + k
  if (idx >= 256 * K) return;
  const int n = idx / K, k = idx % K;
  Wt[idx] = __float2bfloat16(W[k * 256 + n]);
}

// ---------------------------------------------------------------------------
// build fused edge weight Wt[768 n][768 k] bf16
// h-k axis: [0,256)=pre_n[src], [256,512)=pre_e, [512,768)=pre_n[dst].
// ---------------------------------------------------------------------------
__global__ void build_wt_kernel(const float* __restrict__ Wpa,
                                const float* __restrict__ Wsa,
                                const float* __restrict__ Wet,
                                __hip_bfloat16* __restrict__ Wt) {
  const int idx = blockIdx.x * 256 + threadIdx.x;  // n*768 + k
  if (idx >= 768 * 768) return;
  const int n = idx / 768, k = idx % 768;
  float v = 0.f;
  if (n < 256) {
    if (k < 512) v = Wpa[k * 256 + n];
  } else if (n < 512) {
    const int nn = n - 256;
    if (k >= 512) v = Wsa[(k - 512) * 256 + nn];
    else if (k >= 256) v = Wsa[k * 256 + nn];
  } else {
    v = Wet[k * 256 + (n - 512)];
  }
  Wt[idx] = __float2bfloat16(v);
}

// ---------------------------------------------------------------------------
// CSR build: counts, exclusive scan, fill
// ---------------------------------------------------------------------------
__global__ void count_kernel(const int* __restrict__ src, const int* __restrict__ dst,
                             int* __restrict__ cnt_out, int* __restrict__ cnt_in) {
  const int e = blockIdx.x * 256 + threadIdx.x;
  if (e < N_EDGES) {
    atomicAdd(&cnt_out[src[e]], 1);
    atomicAdd(&cnt_in[dst[e]], 1);
  }
}

__global__ __launch_bounds__(256) void scan_kernel(const int* __restrict__ cnt,
                                                   int* __restrict__ offs, int n) {
  __shared__ int part[256];
  const int t  = threadIdx.x;
  const int lo = t * 40;
  const int hi = (lo + 40 < n) ? lo + 40 : n;
  int s = 0;
  for (int i = lo; i < hi; ++i) s += cnt[i];
  part[t] = s;
  __syncthreads();
  for (int off = 1; off < 256; off <<= 1) {
    int v = (t >= off) ? part[t - off] : 0;
    __syncthreads();
    part[t] += v;
    __syncthreads();
  }
  int run = (t == 0) ? 0 : part[t - 1];
  for (int i = lo; i < hi; ++i) { offs[i] = run; run += cnt[i]; }
  if (t == 255) offs[n] = run;
}

__global__ void fill_kernel(const int* __restrict__ src, const int* __restrict__ dst,
                            const int* __restrict__ offs_out, const int* __restrict__ offs_in,
                            int* __restrict__ cur_out, int* __restrict__ cur_in,
                            int* __restrict__ list_out, int* __restrict__ list_in) {
  const int e = blockIdx.x * 256 + threadIdx.x;
  if (e < N_EDGES) {
    const int u = src[e];
    const int p = atomicAdd(&cur_out[u], 1);
    list_out[offs_out[u] + p] = e;
    const int v = dst[e];
    const int q = atomicAdd(&cur_in[v], 1);
    list_in[offs_in[v] + q] = e;
  }
}

// ---------------------------------------------------------------------------
// Generic MFMA GEMM (m97 structure): out[M,256] = act(A[M,K] @ Wt^T + bias)
// A_F32: A is f32 in HBM, converted to bf16 during reg-staged LDS write.
// ---------------------------------------------------------------------------
template <bool RELU, bool F32OUT, bool A_F32>
__global__ __launch_bounds__(256, 2) void gemm_mfma_kernel(
    const void* __restrict__ Av, const __hip_bfloat16* __restrict__ Wt,
    const float* __restrict__ bias, float* __restrict__ outf,
    __hip_bfloat16* __restrict__ outb, int M, int Ksteps) {
  __shared__ char sA[2][16384];
  __shared__ char sW[2][16384];

  const int K    = Ksteps * 64;
  const int row0 = blockIdx.x * 128;
  const int nt   = blockIdx.y;

  const int tid  = threadIdx.x;
  const int lane = tid & 63;
  const int w    = tid >> 6;

  const int rsub  = lane >> 3;
  const int pslot = lane & 7;
  const int sslot = pslot ^ rsub;

  auto stage = [&](int b, int c) {
#pragma unroll
    for (int j = 0; j < 4; ++j) {
      const int r = w * 32 + j * 8 + rsub;
      int ar = row0 + r;
      if (ar >= M) ar = M - 1;
      if constexpr (A_F32) {
        const float* gp = (const float*)Av + (size_t)ar * K + c * 64 + sslot * 8;
        const f32x4 lo = *(const f32x4*)gp;
        const f32x4 hi = *(const f32x4*)(gp + 4);
        union { __hip_bfloat16 h[8]; bf16x8 v; } pk;
#pragma unroll
        for (int q = 0; q < 4; ++q) pk.h[q] = __float2bfloat16(lo[q]);
#pragma unroll
        for (int q = 0; q < 4; ++q) pk.h[4 + q] = __float2bfloat16(hi[q]);
        *(bf16x8*)&sA[b][r * 128 + pslot * 16] = pk.v;
      } else {
        const __hip_bfloat16* gp =
            (const __hip_bfloat16*)Av + (size_t)ar * K + c * 64 + sslot * 8;
        __builtin_amdgcn_global_load_lds(
            (const __attribute__((address_space(1))) void*)gp,
            (__attribute__((address_space(3))) void*)&sA[b][(w * 32 + j * 8) * 128],
            16, 0, 0);
      }
      const __hip_bfloat16* wp = Wt + (size_t)(nt * 128 + r) * K + c * 64 + sslot * 8;
      __builtin_amdgcn_global_load_lds(
          (const __attribute__((address_space(1))) void*)wp,
          (__attribute__((address_space(3))) void*)&sW[b][(w * 32 + j * 8) * 128],
          16, 0, 0);
    }
  };

  const int wm = (w >> 1) * 64;
  const int wn = (w & 1) * 64;

  f32x4 acc[4][4];
#pragma unroll
  for (int i = 0; i < 4; ++i)
#pragma unroll
    for (int j = 0; j < 4; ++j) acc[i][j] = (f32x4)0.f;

  stage(0, 0);
  asm volatile("s_waitcnt vmcnt(0)");
  __syncthreads();

  int buf = 0;
  for (int c = 0; c < Ksteps; ++c) {
    if (c + 1 < Ksteps) stage(buf ^ 1, c + 1);
#pragma unroll
    for (int kk = 0; kk < 2; ++kk) {
      bf16x8 av[4], bv[4];
#pragma unroll
      for (int i = 0; i < 4; ++i) {
        const int row  = wm + i * 16 + (lane & 15);
        const int boff = row * 128 + ((kk * 64 + (lane >> 4) * 16) ^ ((row & 7) << 4));
        av[i] = *(const bf16x8*)&sA[buf][boff];
      }
#pragma unroll
      for (int j = 0; j < 4; ++j) {
        const int nrow = wn + j * 16 + (lane & 15);
        const int boff = nrow * 128 + ((kk * 64 + (lane >> 4) * 16) ^ ((nrow & 7) << 4));
        bv[j] = *(const bf16x8*)&sW[buf][boff];
      }
#pragma unroll
      for (int i = 0; i < 4; ++i)
#pragma unroll
        for (int j = 0; j < 4; ++j)
          acc[i][j] = __builtin_amdgcn_mfma_f32_16x16x32_bf16(av[i], bv[j], acc[i][j], 0, 0, 0);
    }
    __syncthreads();
    buf ^= 1;
  }

#pragma unroll
  for (int i = 0; i < 4; ++i) {
    const int row = row0 + wm + i * 16 + ((lane >> 4) << 2);
#pragma unroll
    for (int j = 0; j < 4; ++j) {
      const int col = nt * 128 + wn + j * 16 + (lane & 15);
      const float bb = bias[col];
#pragma unroll
      for (int r = 0; r < 4; ++r) {
        if (row + r < M) {
          float v = acc[i][j][r] + bb;
          if (RELU) v = v > 0.f ? v : 0.f;
          if (F32OUT) outf[(size_t)(row + r) * 256 + col] = v;
          else        outb[(size_t)(row + r) * 256 + col] = __float2bfloat16(v);
        }
      }
    }
  }
}

// ---------------------------------------------------------------------------
// MFMA edge GEMM with XCD-grouped remap. MSG=true: store bf16 msg_p/msg_s
// (CSR aggregation downstream). MSG=false: legacy f32 atomicAdd fallback.
// ---------------------------------------------------------------------------
template <bool MSG>
__global__ __launch_bounds__(256, 2) void edge_mfma_kernel(
    const __hip_bfloat16* __restrict__ pre_n,
    const __hip_bfloat16* __restrict__ pre_e,
    const __hip_bfloat16* __restrict__ Wt,
    const int* __restrict__ src, const int* __restrict__ dst,
    const float* __restrict__ bpa, const float* __restrict__ bsa,
    const float* __restrict__ bet,
    float* __restrict__ agg_p, float* __restrict__ agg_s,
    __hip_bfloat16* __restrict__ msg_p, __hip_bfloat16* __restrict__ msg_s,
    float* __restrict__ edge_out) {
  __shared__ char sA[2][16384];
  __shared__ char sW[2][16384];
  __shared__ int sSrc[128], sDst[128];

  // XCD-grouped remap (bid -> XCD is bid % 8 on MI355X)
  const int bid = blockIdx.x;
  const int xcd = bid & 7;
  const int s   = xcd * 938 + (bid >> 3);
  const int et  = s / 6;
  const int nt  = s % 6;
  if (et >= N_EDGES / 128) return;
  const int mat = nt >> 1;  // 0=P, 1=S, 2=E
  const int e0  = et * 128;

  const int tid  = threadIdx.x;
  const int lane = tid & 63;
  const int w    = tid >> 6;

  if (tid < 128) sSrc[tid] = src[e0 + tid];
  else           sDst[tid - 128] = dst[e0 + tid - 128];
  __syncthreads();

  const int c_lo = (mat == 1) ? 4 : 0;
  const int c_hi = (mat == 0) ? 8 : 12;

  const int rsub  = lane >> 3;
  const int pslot = lane & 7;
  const int sslot = pslot ^ rsub;

  auto stage = [&](int b, int c) {
#pragma unroll
    for (int j = 0; j < 4; ++j) {
      const int r = w * 32 + j * 8 + rsub;
      const __hip_bfloat16* gp;
      if (c < 4)      gp = pre_n + (size_t)sSrc[r] * 256 + c * 64 + sslot * 8;
      else if (c < 8) gp = pre_e + (size_t)(e0 + r) * 256 + (c - 4) * 64 + sslot * 8;
      else            gp = pre_n + (size_t)sDst[r] * 256 + (c - 8) * 64 + sslot * 8;
      __builtin_amdgcn_global_load_lds(
          (const __attribute__((address_space(1))) void*)gp,
          (__attribute__((address_space(3))) void*)&sA[b][(w * 32 + j * 8) * 128],
          16, 0, 0);
      const __hip_bfloat16* wp =
          Wt + (size_t)(nt * 128 + r) * 768 + c * 64 + sslot * 8;
      __builtin_amdgcn_global_load_lds(
          (const __attribute__((address_space(1))) void*)wp,
          (__attribute__((address_space(3))) void*)&sW[b][(w * 32 + j * 8) * 128],
          16, 0, 0);
    }
  };

  const int wm = (w >> 1) * 64;
  const int wn = (w & 1) * 64;

  f32x4 acc[4][4];
#pragma unroll
  for (int i = 0; i < 4; ++i)
#pragma unroll
    for (int j = 0; j < 4; ++j) acc[i][j] = (f32x4)0.f;

  stage(0, c_lo);
  asm volatile("s_waitcnt vmcnt(0)");
  __syncthreads();

  int buf = 0;
  for (int c = c_lo; c < c_hi; ++c) {
    if (c + 1 < c_hi) stage(buf ^ 1, c + 1);
#pragma unroll
    for (int kk = 0; kk < 2; ++kk) {
      bf16x8 av[4], bv[4];
#pragma unroll
      for (int i = 0; i < 4; ++i) {
        const int row  = wm + i * 16 + (lane & 15);
        const int boff = row * 128 + ((kk * 64 + (lane >> 4) * 16) ^ ((row & 7) << 4));
        av[i] = *(const bf16x8*)&sA[buf][boff];
      }
#pragma unroll
      for (int j = 0; j < 4; ++j) {
        const int nrow = wn + j * 16 + (lane & 15);
        const int boff = nrow * 128 + ((kk * 64 + (lane >> 4) * 16) ^ ((nrow & 7) << 4));
        bv[j] = *(const bf16x8*)&sW[buf][boff];
      }
#pragma unroll
      for (int i = 0; i < 4; ++i)
#pragma unroll
        for (int j = 0; j < 4; ++j)
          acc[i][j] = __builtin_amdgcn_mfma_f32_16x16x32_bf16(av[i], bv[j], acc[i][j], 0, 0, 0);
    }
    __syncthreads();
    buf ^= 1;
  }

  const int colbase = (nt & 1) * 128 + wn;
#pragma unroll
  for (int i = 0; i < 4; ++i) {
    const int row = wm + i * 16 + ((lane >> 4) << 2);
#pragma unroll
    for (int j = 0; j < 4; ++j) {
      const int col = colbase + j * 16 + (lane & 15);
      if (mat == 0) {
        const float bb = bpa[col];
#pragma unroll
        for (int r = 0; r < 4; ++r) {
          float v = acc[i][j][r] + bb;
          v = v > 0.f ? v : 0.f;
          if (MSG) msg_p[(size_t)(e0 + row + r) * 256 + col] = __float2bfloat16(v);
          else     atomicAdd(&agg_p[(size_t)sDst[row + r] * 256 + col], v);
        }
      } else if (mat == 1) {
        const float bb = bsa[col];
#pragma unroll
        for (int r = 0; r < 4; ++r) {
          float v = acc[i][j][r] + bb;
          v = v > 0.f ? v : 0.f;
          if (MSG) msg_s[(size_t)(e0 + row + r) * 256 + col] = __float2bfloat16(v);
          else     atomicAdd(&agg_s[(size_t)sSrc[row + r] * 256 + col], v);
        }
      } else {
        const float bb = bet[col];
#pragma unroll
        for (int r = 0; r < 4; ++r)
          edge_out[(size_t)(e0 + row + r) * 256 + col] = acc[i][j][r] + bb;
      }
    }
  }
}

// ---------------------------------------------------------------------------
// CSR gather-aggregation + nodeH assembly (fuses node_prep).
// Block = 1 node, 128 threads. Wave 0 -> P (in-edges), wave 1 -> S (out-edges).
// Lane = (col-group 0..31) x (edge parity 0..1); 16B loads; shfl_xor combine.
// ---------------------------------------------------------------------------
__global__ __launch_bounds__(128) void agg_kernel(
    const __hip_bfloat16* __restrict__ msg_p, const __hip_bfloat16* __restrict__ msg_s,
    const __hip_bfloat16* __restrict__ pre_n,
    const int* __restrict__ offs_in, const int* __restrict__ list_in,
    const int* __restrict__ offs_out, const int* __restrict__ list_out,
    __hip_bfloat16* __restrict__ nodeH) {
  const int v    = blockIdx.x;
  const int wave = threadIdx.x >> 6;
  const int lane = threadIdx.x & 63;
  const int cg   = lane & 31;   // col group: cols cg*8..cg*8+7
  const int par  = lane >> 5;   // edge parity

  const int* offs = wave ? offs_out : offs_in;
  const int* list = wave ? list_out : list_in;
  const __hip_bfloat16* msg = wave ? msg_s : msg_p;

  const int p0 = offs[v], p1 = offs[v + 1];
  float acc[8];
#pragma unroll
  for (int k = 0; k < 8; ++k) acc[k] = 0.f;

  for (int i = p0 + par; i < p1; i += 2) {
    const int e = list[i];
    const uint4 u = *(const uint4*)(msg + (size_t)e * 256 + cg * 8);
    const unsigned short* h = (const unsigned short*)&u;
#pragma unroll
    for (int k = 0; k < 8; ++k) acc[k] += __uint_as_float((unsigned)h[k] << 16);
  }
#pragma unroll
  for (int k = 0; k < 8; ++k) acc[k] += __shfl_xor(acc[k], 32);

  if (par == 0) {
    const int deg = p1 - p0;
    const float inv = 1.f / (float)(deg > 1 ? deg : 1);
    union { __hip_bfloat16 h[8]; uint4 u; } o;
#pragma unroll
    for (int k = 0; k < 8; ++k) o.h[k] = __float2bfloat16(acc[k] * inv);
    *(uint4*)(nodeH + (size_t)v * 768 + wave * 512 + cg * 8) = o.u;
  } else if (wave == 0) {
    // middle third: pre_n copy (cols cg*8..cg*8+7)
    const uint4 u = *(const uint4*)(pre_n + (size_t)v * 256 + cg * 8);
    *(uint4*)(nodeH + (size_t)v * 768 + 256 + cg * 8) = u;
  }
}

// ---------------------------------------------------------------------------
// fallback node prep (atomic path): nodeH from f32 agg buffers + int degrees
// ---------------------------------------------------------------------------
__global__ void node_prep_kernel(const float* __restrict__ agg_p,
                                 const float* __restrict__ agg_s,
                                 const __hip_bfloat16* __restrict__ pre_n,
                                 const int* __restrict__ cnt_in,
                                 const int* __restrict__ cnt_out,
                                 __hip_bfloat16* __restrict__ nodeH) {
  const int row = blockIdx.x;
  const int c   = threadIdx.x;
  const float di = (float)(cnt_in[row]  > 1 ? cnt_in[row]  : 1);
  const float dd = (float)(cnt_out[row] > 1 ? cnt_out[row] : 1);
  nodeH[(size_t)row * 768 + c]       = __float2bfloat16(agg_p[(size_t)row * 256 + c] / di);
  nodeH[(size_t)row * 768 + 256 + c] = pre_n[(size_t)row * 256 + c];
  nodeH[(size_t)row * 768 + 512 + c] = __float2bfloat16(agg_s[(size_t)row * 256 + c] / dd);
}

// ---------------------------------------------------------------------------
extern "C" void kernel_launch(void* const* d_in, const int* in_sizes, int n_in,
                              void* d_out, int out_size, void* d_ws, size_t ws_size,
                              hipStream_t stream) {
  const float* x         = (const float*)d_in[0];
  const float* edge_feat = (const float*)d_in[1];
  const int*   edge_idx  = (const int*)d_in[2];
  const float* Wn  = (const float*)d_in[3];
  const float* bn  = (const float*)d_in[4];
  const float* We  = (const float*)d_in[5];
  const float* be  = (const float*)d_in[6];
  const float* Wpa = (const float*)d_in[7];
  const float* bpa = (const float*)d_in[8];
  const float* Wsa = (const float*)d_in[9];
  const float* bsa = (const float*)d_in[10];
  const float* Wnt = (const float*)d_in[11];
  const float* bnt = (const float*)d_in[12];
  const float* Wet = (const float*)d_in[13];
  const float* bet = (const float*)d_in[14];

  const int* src = edge_idx;
  const int* dst = edge_idx + N_EDGES;

  float* node_out = (float*)d_out;
  float* edge_out = (float*)d_out + (size_t)N_NODES * DD;

  char* p = (char*)d_ws;
  auto alloc = [&](size_t bytes) -> void* {
    void* r = (void*)p;
    p += (bytes + 255) & ~(size_t)255;
    return r;
  };

  // common buffers
  __hip_bfloat16* pre_n_bf = (__hip_bfloat16*)alloc((size_t)N_NODES * DD * 2);
  __hip_bfloat16* pre_e_bf = (__hip_bfloat16*)alloc((size_t)N_EDGES * DD * 2);
  __hip_bfloat16* nodeH    = (__hip_bfloat16*)alloc((size_t)N_NODES * 768 * 2);
  __hip_bfloat16* Wt_edge  = (__hip_bfloat16*)alloc((size_t)768 * 768 * 2);
  __hip_bfloat16* Wn_t     = (__hip_bfloat16*)alloc((size_t)256 * 256 * 2);
  __hip_bfloat16* We_t     = (__hip_bfloat16*)alloc((size_t)256 * 128 * 2);
  __hip_bfloat16* Wnt_t    = (__hip_bfloat16*)alloc((size_t)256 * 768 * 2);
  int* csr_zero = (int*)alloc(4 * (size_t)N_NODES * 4);  // cnt_in|cnt_out|cur_in|cur_out
  int* cnt_in   = csr_zero;
  int* cnt_out  = csr_zero + N_NODES;
  int* cur_in   = csr_zero + 2 * N_NODES;
  int* cur_out  = csr_zero + 3 * N_NODES;
  int* offs_in  = (int*)alloc(((size_t)N_NODES + 1) * 4);
  int* offs_out = (int*)alloc(((size_t)N_NODES + 1) * 4);
  int* list_in  = (int*)alloc((size_t)N_EDGES * 4);
  int* list_out = (int*)alloc((size_t)N_EDGES * 4);

  // mode-dependent buffers
  const size_t msg_bytes = (size_t)N_EDGES * DD * 2;           // 82 MB each
  const size_t base_used = (size_t)(p - (char*)d_ws);
  const bool msg_mode = ws_size >= base_used + 2 * msg_bytes + 512;

  __hip_bfloat16* msg_p = nullptr;
  __hip_bfloat16* msg_s = nullptr;
  float* agg_p = nullptr;
  float* agg_s = nullptr;
  if (msg_mode) {
    msg_p = (__hip_bfloat16*)alloc(msg_bytes);
    msg_s = (__hip_bfloat16*)alloc(msg_bytes);
  } else {
    agg_p = (float*)alloc((size_t)N_NODES * DD * 4);
    agg_s = (float*)alloc((size_t)N_NODES * DD * 4);
  }

  // zero CSR counters/cursors (+ agg buffers in fallback)
  hipMemsetAsync(csr_zero, 0, 4 * (size_t)N_NODES * 4, stream);
  if (!msg_mode)
    hipMemsetAsync(agg_p, 0, 2 * (size_t)N_NODES * DD * 4, stream);

  // weight prep
  wtrans_kernel<<<(256 * 256 + 255) / 256, 256, 0, stream>>>(Wn, Wn_t, 256);
  wtrans_kernel<<<(256 * 128 + 255) / 256, 256, 0, stream>>>(We, We_t, 128);
  wtrans_kernel<<<(256 * 768 + 255) / 256, 256, 0, stream>>>(Wnt, Wnt_t, 768);
  build_wt_kernel<<<(768 * 768 + 255) / 256, 256, 0, stream>>>(Wpa, Wsa, Wet, Wt_edge);

  // CSR build (counts also serve as degrees in fallback)
  count_kernel<<<(N_EDGES + 255) / 256, 256, 0, stream>>>(src, dst, cnt_out, cnt_in);
  if (msg_mode) {
    scan_kernel<<<1, 256, 0, stream>>>(cnt_in, offs_in, N_NODES);
    scan_kernel<<<1, 256, 0, stream>>>(cnt_out, offs_out, N_NODES);
    fill_kernel<<<(N_EDGES + 255) / 256, 256, 0, stream>>>(
        src, dst, offs_out, offs_in, cur_out, cur_in, list_out, list_in);
  }

  // pretrans GEMMs (f32 A, fused convert; relu; bf16 out)
  {
    dim3 g((N_NODES + 127) / 128, 2);
    gemm_mfma_kernel<true, false, true><<<g, 256, 0, stream>>>(
        x, Wn_t, bn, nullptr, pre_n_bf, N_NODES, 4);
  }
  {
    dim3 g(N_EDGES / 128, 2);
    gemm_mfma_kernel<true, false, true><<<g, 256, 0, stream>>>(
        edge_feat, We_t, be, nullptr, pre_e_bf, N_EDGES, 2);
  }

  // fused edge GEMM
  if (msg_mode) {
    edge_mfma_kernel<true><<<7504, 256, 0, stream>>>(
        pre_n_bf, pre_e_bf, Wt_edge, src, dst, bpa, bsa, bet,
        nullptr, nullptr, msg_p, msg_s, edge_out);
    agg_kernel<<<N_NODES, 128, 0, stream>>>(
        msg_p, msg_s, pre_n_bf, offs_in, list_in, offs_out, list_out, nodeH);
  } else {
    edge_mfma_kernel<false><<<7504, 256, 0, stream>>>(
        pre_n_bf, pre_e_bf, Wt_edge, src, dst, bpa, bsa, bet,
        agg_p, agg_s, nullptr, nullptr, edge_out);
    node_prep_kernel<<<N_NODES, 256, 0, stream>>>(
        agg_p, agg_s, pre_n_bf, cnt_in, cnt_out, nodeH);
  }

  // node transformer GEMM
  {
    dim3 g((N_NODES + 127) / 128, 2);
    gemm_mfma_kernel<false, true, false><<<g, 256, 0, stream>>>(
        nodeH, Wnt_t, bnt, node_out, nullptr, N_NODES, 12);
  }
}